// Round 6
// baseline (159.923 us; speedup 1.0000x reference)
//
#include <hip/hip_runtime.h>
#include <hip/hip_bf16.h>

typedef __bf16 bf16x8 __attribute__((ext_vector_type(8)));
typedef unsigned short u16x8 __attribute__((ext_vector_type(8)));
typedef unsigned short u16x4 __attribute__((ext_vector_type(4)));
typedef float f32x4 __attribute__((ext_vector_type(4)));

#define MFMA(a, b, c) __builtin_amdgcn_mfma_f32_16x16x32_bf16(a, b, c, 0, 0, 0)

#define LQ 2048
#define DD 256

static __device__ __forceinline__ float bf2f(unsigned short u) {
  union { unsigned int i; float f; } x; x.i = ((unsigned int)u) << 16; return x.f;
}
static __device__ __forceinline__ unsigned short f2bf(float f) {
  union { float f; unsigned int i; } x; x.f = f;
  unsigned int r = x.i + 0x7fffu + ((x.i >> 16) & 1u);  // RNE
  return (unsigned short)(r >> 16);
}
static __device__ __forceinline__ void gll16(const void* g, void* l) {
  __builtin_amdgcn_global_load_lds(
      (const __attribute__((address_space(1))) unsigned int*)g,
      (__attribute__((address_space(3))) unsigned int*)l, 16, 0, 0);
}

// ---------- weight transpose: W f32 [K][N] -> WT bf16 [N][K] ----------
__global__ void wt_kernel(const float* __restrict__ W, unsigned short* __restrict__ WT,
                          int logK, int N) {
  int K = 1 << logK;
  int id = blockIdx.x * 256 + threadIdx.x;
  if (id >= K * N) return;
  int n = id >> logK;
  int k = id & (K - 1);
  WT[id] = f2bf(W[(long)k * N + n]);
}

// ---------- projection GEMM: out bf16[M][256] = A f32[M][Kd] @ W (+bias) ----------
__global__ __launch_bounds__(256) void proj_kernel(
    const float* __restrict__ A, const unsigned short* __restrict__ WT,
    const float* __restrict__ bias, unsigned short* __restrict__ outb,
    unsigned short* __restrict__ outT, int Kd) {
  __shared__ unsigned short A_s[128 * 32];
  __shared__ unsigned short B_s[128 * 32];
  const int tid = threadIdx.x;
  const int w = tid >> 6, lane = tid & 63, g = lane >> 4, c = lane & 15;
  const int m0 = (blockIdx.x >> 1) * 128, n0 = (blockIdx.x & 1) * 128;
  const int wr = (w >> 1) * 64, wc = (w & 1) * 64;

  f32x4 acc[4][4];
  const f32x4 z4 = {0.f, 0.f, 0.f, 0.f};
  for (int i = 0; i < 4; i++)
    for (int j = 0; j < 4; j++) acc[i][j] = z4;

  const int row_st = tid >> 1, k0 = (tid & 1) * 16;
  const unsigned swz_w = (unsigned)((row_st & 7) << 4);
  const int nk = Kd >> 5;
  for (int ks = 0; ks < nk; ks++) {
    {
      const float* src = A + (long)(m0 + row_st) * Kd + ks * 32 + k0;
      f32x4 a0 = *(const f32x4*)(src);
      f32x4 a1 = *(const f32x4*)(src + 4);
      f32x4 a2 = *(const f32x4*)(src + 8);
      f32x4 a3 = *(const f32x4*)(src + 12);
      bf16x8 t0, t1;
#pragma unroll
      for (int j = 0; j < 4; j++) {
        t0[j] = (__bf16)a0[j]; t0[4 + j] = (__bf16)a1[j];
        t1[j] = (__bf16)a2[j]; t1[4 + j] = (__bf16)a3[j];
      }
      *(bf16x8*)((char*)A_s + (((unsigned)(row_st * 64 + k0 * 2)) ^ swz_w)) = t0;
      *(bf16x8*)((char*)A_s + (((unsigned)(row_st * 64 + k0 * 2 + 16)) ^ swz_w)) = t1;
      const unsigned short* srcB = WT + (long)(n0 + row_st) * Kd + ks * 32 + k0;
      u16x8 b0 = *(const u16x8*)srcB;
      u16x8 b1 = *(const u16x8*)(srcB + 8);
      *(u16x8*)((char*)B_s + (((unsigned)(row_st * 64 + k0 * 2)) ^ swz_w)) = b0;
      *(u16x8*)((char*)B_s + (((unsigned)(row_st * 64 + k0 * 2 + 16)) ^ swz_w)) = b1;
    }
    __syncthreads();
    bf16x8 af[4], bfr[4];
    for (int rf = 0; rf < 4; rf++) {
      int row = wr + rf * 16 + c;
      af[rf] = *(const bf16x8*)((char*)A_s +
                (((unsigned)(row * 64 + g * 16)) ^ ((row & 7) << 4)));
    }
    for (int cf = 0; cf < 4; cf++) {
      int row = wc + cf * 16 + c;
      bfr[cf] = *(const bf16x8*)((char*)B_s +
                (((unsigned)(row * 64 + g * 16)) ^ ((row & 7) << 4)));
    }
    for (int rf = 0; rf < 4; rf++)
      for (int cf = 0; cf < 4; cf++)
        acc[rf][cf] = MFMA(af[rf], bfr[cf], acc[rf][cf]);
    __syncthreads();
  }
  for (int cf = 0; cf < 4; cf++) {
    const int col = n0 + wc + cf * 16 + c;
    const float bv = bias[col];
    for (int rf = 0; rf < 4; rf++) {
      const int row0 = m0 + wr + rf * 16 + g * 4;
      unsigned short pk[4];
      for (int i = 0; i < 4; i++) {
        float v = acc[rf][cf][i] + bv;
        pk[i] = f2bf(v);
        outb[(long)(row0 + i) * 256 + col] = pk[i];
      }
      if (outT) {
        const int b = row0 >> 11;
        const int key0 = row0 & 2047;
        unsigned long long packed = (unsigned long long)pk[0] |
                                    ((unsigned long long)pk[1] << 16) |
                                    ((unsigned long long)pk[2] << 32) |
                                    ((unsigned long long)pk[3] << 48);
        *(unsigned long long*)(outT + ((long)(b * 256 + col) * LQ + key0)) = packed;
      }
    }
  }
}

// ---------- flash attention: 32 q-rows/wave, NSPLIT-way key split ----------
// Block: 4 waves x 32 rows = 128 q-rows; keys [ksplit*2048/NSPLIT, +2048/NSPLIT).
// Ks slot (ks,g,key): byte ks*2048+g*512+key*16 = K[k0+key][ks*32+g*8..+8]
// KTs slot (f,g,c):   byte f*1024+g*256+c*16   = KT[f*16+c][k0+g*8..+8]
// Last split writes f32 partial to out; others bf16 to Op[ksplit].
template <int NSPLIT>
__global__ __launch_bounds__(256, 2) void attn_kernel(
    const unsigned short* __restrict__ Qb, const unsigned short* __restrict__ Kb,
    const unsigned short* __restrict__ KTb, unsigned short* __restrict__ Op,
    float* __restrict__ out, float* __restrict__ ML) {
  constexpr int KS = 2048 / NSPLIT;   // keys per block
  constexpr int NT = KS / 32;         // 32-key tiles
  constexpr int NBLK = 128 * NSPLIT;  // grid size
  __shared__ char Ks[2][16384];
  __shared__ char KTs[2][16384];
  __shared__ char Ps[4][2048];
  const int tid = threadIdx.x;
  const int w = tid >> 6, lane = tid & 63, g = lane >> 4, c = lane & 15;
  const int lid = (blockIdx.x & 7) * (NBLK / 8) + (blockIdx.x >> 3);  // XCD-chunked
  const int ksplit = lid & (NSPLIT - 1), qg = lid / NSPLIT;  // qg 0..127
  const int b = qg >> 4;
  const long qrow0 = (long)qg * 128;
  const int kbase = ksplit * KS;
  const float CS = 0.03125f * 1.4426950408889634f;  // SCALE * log2(e)
  const float THRM = 8.0f / CS;                     // defer-max threshold (raw)

  // Q A-fragments: 2 row-frags x 8 k-steps
  bf16x8 qa[2][8];
#pragma unroll
  for (int r = 0; r < 2; r++) {
    const unsigned short* qr = Qb + (qrow0 + w * 32 + r * 16 + c) * DD + g * 8;
#pragma unroll
    for (int ks = 0; ks < 8; ks++) qa[r][ks] = *(const bf16x8*)(qr + ks * 32);
  }
  f32x4 o[2][16];
  const f32x4 z4 = {0.f, 0.f, 0.f, 0.f};
#pragma unroll
  for (int r = 0; r < 2; r++)
#pragma unroll
    for (int f = 0; f < 16; f++) o[r][f] = z4;
  float m_[2][4], l_[2][4];
#pragma unroll
  for (int r = 0; r < 2; r++)
#pragma unroll
    for (int i = 0; i < 4; i++) { m_[r][i] = -1e30f; l_[r][i] = 0.f; }

  const char* kb_b = (const char*)(Kb + (long)b * LQ * DD);
  const char* kt_b = (const char*)(KTb + (long)b * DD * LQ);

  const int ks_w = w >> 1;
  const int kg_w = ((w & 1) << 1) + (lane >> 5);
  const int kkey = lane & 31;

#define STAGE(buf, kt_)                                                         \
  {                                                                             \
    const int k0_ = kbase + (kt_) * 32;                                         \
    _Pragma("unroll") for (int i = 0; i < 4; i++) {                             \
      gll16(kb_b + (long)(k0_ + kkey) * 512 + (i * 2 + ks_w) * 64 + kg_w * 16,  \
            Ks[buf] + i * 4096 + w * 1024);                                     \
    }                                                                           \
    _Pragma("unroll") for (int i = 0; i < 4; i++) {                             \
      const int f_ = i * 4 + w;                                                 \
      gll16(kt_b + (long)(f_ * 16 + c) * 4096 + (long)k0_ * 2 + g * 16,         \
            KTs[buf] + f_ * 1024);                                              \
    }                                                                           \
  }

  STAGE(0, 0);
  for (int kt = 0; kt < NT; kt++) {
    const int cur = kt & 1;
    __syncthreads();
    if (kt + 1 < NT) STAGE(cur ^ 1, kt + 1);

    // ---- S = Q K^T (B-frags shared across both row-frags) ----
    const char* kread = Ks[cur] + g * 512 + c * 16;
    f32x4 s[2][2];
    s[0][0] = z4; s[0][1] = z4; s[1][0] = z4; s[1][1] = z4;
#pragma unroll
    for (int ks = 0; ks < 8; ks++) {
      bf16x8 kb0 = *(const bf16x8*)(kread + ks * 2048);
      bf16x8 kb1 = *(const bf16x8*)(kread + ks * 2048 + 256);
      s[0][0] = MFMA(qa[0][ks], kb0, s[0][0]);
      s[0][1] = MFMA(qa[0][ks], kb1, s[0][1]);
      s[1][0] = MFMA(qa[1][ks], kb0, s[1][0]);
      s[1][1] = MFMA(qa[1][ks], kb1, s[1][1]);
    }
    // ---- online softmax with defer-max ----
    float m2[2][4];
#pragma unroll
    for (int r = 0; r < 2; r++)
#pragma unroll
      for (int i = 0; i < 4; i++) m2[r][i] = fmaxf(s[r][0][i], s[r][1][i]);
#pragma unroll
    for (int msk = 1; msk <= 8; msk <<= 1)
#pragma unroll
      for (int r = 0; r < 2; r++)
#pragma unroll
        for (int i = 0; i < 4; i++)
          m2[r][i] = fmaxf(m2[r][i], __shfl_xor(m2[r][i], msk, 64));
    bool grew = false;
#pragma unroll
    for (int r = 0; r < 2; r++)
#pragma unroll
      for (int i = 0; i < 4; i++) grew |= (m2[r][i] > m_[r][i] + THRM);
    if (__any(grew)) {
#pragma unroll
      for (int r = 0; r < 2; r++)
#pragma unroll
        for (int i = 0; i < 4; i++) {
          float mn = fmaxf(m_[r][i], m2[r][i]);
          float al = exp2f((m_[r][i] - mn) * CS);
          m_[r][i] = mn;
          l_[r][i] *= al;
#pragma unroll
          for (int f = 0; f < 16; f++) o[r][f][i] *= al;
        }
    }
    // ---- P -> LDS (swizzled), read back as A-frags ----
#pragma unroll
    for (int r = 0; r < 2; r++)
#pragma unroll
      for (int i = 0; i < 4; i++) {
        const int row = r * 16 + 4 * g + i;
        const unsigned swz = (unsigned)(i << 4);
        float p0 = exp2f((s[r][0][i] - m_[r][i]) * CS);
        float p1 = exp2f((s[r][1][i] - m_[r][i]) * CS);
        l_[r][i] += p0 + p1;
        char* base = Ps[w] + row * 64;
        *(__bf16*)(base + ((unsigned)(c * 2) ^ swz)) = (__bf16)p0;
        *(__bf16*)(base + ((unsigned)(32 + c * 2) ^ swz)) = (__bf16)p1;
      }
    asm volatile("" ::: "memory");
    bf16x8 pa[2];
#pragma unroll
    for (int r = 0; r < 2; r++)
      pa[r] = *(const bf16x8*)(Ps[w] + (r * 16 + c) * 64 +
                               (((unsigned)(g * 16)) ^ ((unsigned)(c & 3) << 4)));
    // ---- O += P @ V (V-frags shared across both row-frags) ----
    const char* vread = KTs[cur] + g * 256 + c * 16;
#pragma unroll
    for (int f = 0; f < 16; f++) {
      bf16x8 vb = *(const bf16x8*)(vread + f * 1024);
      o[0][f] = MFMA(pa[0], vb, o[0][f]);
      o[1][f] = MFMA(pa[1], vb, o[1][f]);
    }
  }
#undef STAGE

#pragma unroll
  for (int msk = 1; msk <= 8; msk <<= 1)
#pragma unroll
    for (int r = 0; r < 2; r++)
#pragma unroll
      for (int i = 0; i < 4; i++) l_[r][i] += __shfl_xor(l_[r][i], msk, 64);

  if (ksplit == NSPLIT - 1) {
    float* op = out + qrow0 * DD;
#pragma unroll
    for (int r = 0; r < 2; r++)
#pragma unroll
      for (int f = 0; f < 16; f++)
#pragma unroll
        for (int i = 0; i < 4; i++)
          op[(w * 32 + r * 16 + g * 4 + i) * DD + f * 16 + c] = o[r][f][i];
  } else {
    unsigned short* op = Op + (long)ksplit * (16384 * 256) + qrow0 * DD;
#pragma unroll
    for (int r = 0; r < 2; r++)
#pragma unroll
      for (int f = 0; f < 16; f++)
#pragma unroll
        for (int i = 0; i < 4; i++)
          op[(w * 32 + r * 16 + g * 4 + i) * DD + f * 16 + c] = f2bf(o[r][f][i]);
  }
  if (c == 0) {
    float* mlp = ML + (qg * NSPLIT + ksplit) * 256;
#pragma unroll
    for (int r = 0; r < 2; r++)
#pragma unroll
      for (int i = 0; i < 4; i++) {
        const int row = w * 32 + r * 16 + g * 4 + i;
        mlp[row] = m_[r][i];
        mlp[128 + row] = l_[r][i];
      }
  }
}

// ---------- merge the NSPLIT key-split partials + residual ----------
template <int NSPLIT>
__global__ __launch_bounds__(256) void merge_kernel(
    const unsigned short* __restrict__ Op, const float* __restrict__ ML,
    const unsigned short* __restrict__ Qb, float* __restrict__ out) {
  const float CS = 0.03125f * 1.4426950408889634f;
  const long gid = (long)blockIdx.x * 256 + threadIdx.x;
  const long idx = gid * 8;
  const int row = (int)(idx >> 8);
  const int qg = row >> 7, qr = row & 127;
  const float* mlb = ML + (long)(qg * NSPLIT) * 256;
  float mv[NSPLIT], lv[NSPLIT];
#pragma unroll
  for (int k = 0; k < NSPLIT; k++) {
    mv[k] = mlb[k * 256 + qr];
    lv[k] = mlb[k * 256 + 128 + qr];
  }
  float M = mv[0];
#pragma unroll
  for (int k = 1; k < NSPLIT; k++) M = fmaxf(M, mv[k]);
  float ek[NSPLIT], wsum = 0.f;
#pragma unroll
  for (int k = 0; k < NSPLIT; k++) {
    ek[k] = exp2f((mv[k] - M) * CS);
    wsum += ek[k] * lv[k];
  }
  const float inv = 1.0f / wsum;
  float acc[8];
  {
    f32x4 pa = *(const f32x4*)(out + idx);
    f32x4 pb = *(const f32x4*)(out + idx + 4);
#pragma unroll
    for (int e = 0; e < 4; e++) { acc[e] = ek[NSPLIT - 1] * pa[e]; acc[4 + e] = ek[NSPLIT - 1] * pb[e]; }
  }
#pragma unroll
  for (int k = 0; k < NSPLIT - 1; k++) {
    u16x8 p = *(const u16x8*)(Op + (long)k * (16384 * 256) + idx);
#pragma unroll
    for (int e = 0; e < 8; e++) acc[e] += ek[k] * bf2f(p[e]);
  }
  u16x8 qv = *(const u16x8*)(Qb + idx);
  f32x4 ra, rb;
#pragma unroll
  for (int e = 0; e < 4; e++) ra[e] = acc[e] * inv + bf2f(qv[e]);
#pragma unroll
  for (int e = 0; e < 4; e++) rb[e] = acc[4 + e] * inv + bf2f(qv[4 + e]);
  *(f32x4*)(out + idx) = ra;
  *(f32x4*)(out + idx + 4) = rb;
}

extern "C" void kernel_launch(void* const* d_in, const int* in_sizes, int n_in,
                              void* d_out, int out_size, void* d_ws, size_t ws_size,
                              hipStream_t stream) {
  (void)in_sizes; (void)n_in; (void)out_size;
  const float* data1 = (const float*)d_in[0];  // [8,2048,1024]
  const float* data2 = (const float*)d_in[1];  // [8,2048,256]
  const float* Wq = (const float*)d_in[2];     // [1024,256]
  const float* bq = (const float*)d_in[3];     // [256]
  const float* Wk = (const float*)d_in[4];     // [256,256]
  const float* bk = (const float*)d_in[5];     // [256]
  float* out = (float*)d_out;                  // [8,2048,256] f32

  char* ws = (char*)d_ws;
  unsigned short* Qb  = (unsigned short*)(ws);                        // 8 MB
  unsigned short* Kb  = (unsigned short*)(ws + (8ull << 20));         // 8 MB
  unsigned short* KTb = (unsigned short*)(ws + (16ull << 20));        // 8 MB
  unsigned short* WqT = (unsigned short*)(ws + (24ull << 20));        // 512 KB
  unsigned short* WkT = (unsigned short*)(ws + (24ull << 20) + (512u << 10));  // 128 KB
  unsigned short* Op  = (unsigned short*)(ws + (25ull << 20));        // up to 3 x 8 MB

  wt_kernel<<<dim3(1024), dim3(256), 0, stream>>>(Wq, WqT, 10, 256);
  wt_kernel<<<dim3(256), dim3(256), 0, stream>>>(Wk, WkT, 8, 256);
  proj_kernel<<<dim3(256), dim3(256), 0, stream>>>(data1, WqT, bq, Qb,
                                                   (unsigned short*)nullptr, 1024);
  proj_kernel<<<dim3(256), dim3(256), 0, stream>>>(data2, WkT, bk, Kb, KTb, 256);

  if (ws_size >= (50ull << 20)) {
    // 4-way key split: 512 blocks (2/CU, 8 waves/CU); ML after 3 partials
    float* MLb = (float*)(ws + (49ull << 20));                        // 512 KB
    attn_kernel<4><<<dim3(512), dim3(256), 0, stream>>>(Qb, Kb, KTb, Op, out, MLb);
    merge_kernel<4><<<dim3(2048), dim3(256), 0, stream>>>(Op, MLb, Qb, out);
  } else {
    // fallback: 2-way split, 256 blocks; fits in 33.25 MB
    float* MLb = (float*)(ws + (33ull << 20));                        // 256 KB
    attn_kernel<2><<<dim3(256), dim3(256), 0, stream>>>(Qb, Kb, KTb, Op, out, MLb);
    merge_kernel<2><<<dim3(2048), dim3(256), 0, stream>>>(Op, MLb, Qb, out);
  }
}